// Round 8
// baseline (80.905 us; speedup 1.0000x reference)
//
#include <hip/hip_runtime.h>
#include <hip/hip_bf16.h>

#define B_  512
#define T_  256
#define C_  384
#define H_  64
#define SCALE_ 0.05103103630798287f   // 384^-0.5

typedef float f32x4  __attribute__((ext_vector_type(4)));
typedef short bf16x8 __attribute__((ext_vector_type(8)));
typedef short bf16x4 __attribute__((ext_vector_type(4)));

__device__ __forceinline__ unsigned short f2bf(float f) {
    union { float f; unsigned u; } v; v.f = f;
    unsigned r = v.u + 0x7FFFu + ((v.u >> 16) & 1u);   // RNE
    return (unsigned short)(r >> 16);
}

__device__ __forceinline__ unsigned cvt_pk_bf16(float lo, float hi) {
    unsigned r;
    asm("v_cvt_pk_bf16_f32 %0, %1, %2" : "=v"(r) : "v"(lo), "v"(hi));
    return r;
}

// XOR-swizzled [R][64]-short tile index (row = 128 B = 8 x 16B blocks).
__device__ __forceinline__ int swz64(int row, int col) {
    return row * 64 + (((col >> 3) ^ (row & 7)) << 3) + (col & 7);
}

// XOR-swizzled W^T tile: Wl[192][384] shorts, 16B-block index XOR'd by row&7.
__device__ __forceinline__ int wlidx(int row, int k) {
    return row * 384 + ((((k >> 3) ^ (row & 7))) << 3) + (k & 7);
}

// LDS (shorts): smem[73728] = 147456 B.
//  Phase-1 view:  Wl[192][384] swizzled (full W^T resident, bf16)
//  Phase-2 view (alias, written only after all Wl reads):
//    [0,     10240)  Pb: 16 waves x [16][40] swizzled
//    [10240, 26624)  Ks[256][64] swz64
//    [26624, 43008)  Qs[256][64] swz64
//    [43008, 59392)  Vt[64][256] swizzled (h-major)
//
// Phase 1 barrier-free: x A-frags per-lane from global; B-frags ds_read_b128 from Wl.
// Wave grid: 8 row-bands (32 rows = 2 strips) x 2 col-halves (96 cols = 6 frags).
// 3 barriers total.
__global__ __launch_bounds__(1024, 4) void att_head_kernel(
    const float* __restrict__ x,  const float* __restrict__ Wk,
    const float* __restrict__ Wq, const float* __restrict__ Wv,
    float* __restrict__ out)
{
    __shared__ __align__(16) short smem[73728];

    const int tid  = threadIdx.x;
    const int b    = blockIdx.x;
    const int w    = tid >> 6;        // 0..15
    const int lane = tid & 63;
    const int g    = lane >> 4;
    const int i    = lane & 15;
    const int wr   = w >> 1;          // row band (32 rows)
    const int wc   = w & 1;           // col half (96 cols)

    const float* xb = x + (size_t)b * T_ * C_;

    // ---- Stage W^T -> Wl once. Wave w covers k in [24w, 24w+24). Coalesced float4
    //      reads (rows of W), k-pairs packed to b32, swizzled scatter (8-way b32). ----
    {
        const float* Wsrc[3] = { Wk, Wq, Wv };
        #pragma unroll
        for (int m = 0; m < 3; m++) {
            #pragma unroll
            for (int it = 0; it < 3; it++) {
                const int ke = 24 * w + 8 * it + 2 * g;            // even k
                const float4 fa = *(const float4*)(Wsrc[m] + (size_t)ke * H_ + 4 * i);
                const float4 fb = *(const float4*)(Wsrc[m] + (size_t)(ke + 1) * H_ + 4 * i);
                const float* fap = (const float*)&fa;
                const float* fbp = (const float*)&fb;
                #pragma unroll
                for (int c = 0; c < 4; c++) {
                    const int row = m * 64 + 4 * i + c;            // n
                    const unsigned u = cvt_pk_bf16(fap[c], fbp[c]); // {W[ke][n], W[ke+1][n]}
                    *(unsigned*)&smem[wlidx(row, ke)] = u;
                }
            }
        }
    }
    asm volatile("s_waitcnt lgkmcnt(0)\n\ts_barrier" ::: "memory");

    // ---- Phase 1: QKV projection, 6 chunks of k=64, NO barriers ----
    const float* xs0 = xb + (size_t)(32 * wr + i) * C_ + g * 8;   // strip 0 rows
    const float* xs1 = xs0 + 16 * C_;                             // strip 1 rows
    const int browbase = (96 * wc + i) * 384;                     // Wl row base (+ nb*16*384)

    f32x4 accP[2][6];
    #pragma unroll
    for (int m = 0; m < 2; m++)
        #pragma unroll
        for (int nb = 0; nb < 6; nb++) accP[m][nb] = f32x4{0.f, 0.f, 0.f, 0.f};

    #pragma unroll 2
    for (int j = 0; j < 6; j++) {
        float4 xv[2][4];
        #pragma unroll
        for (int ks = 0; ks < 2; ks++) {
            xv[0][2 * ks]     = *(const float4*)(xs0 + 64 * j + 32 * ks);
            xv[0][2 * ks + 1] = *(const float4*)(xs0 + 64 * j + 32 * ks + 4);
            xv[1][2 * ks]     = *(const float4*)(xs1 + 64 * j + 32 * ks);
            xv[1][2 * ks + 1] = *(const float4*)(xs1 + 64 * j + 32 * ks + 4);
        }
        bf16x8 afs[2][2];
        #pragma unroll
        for (int m = 0; m < 2; m++)
            #pragma unroll
            for (int ks = 0; ks < 2; ks++) {
                union { bf16x8 v; unsigned u[4]; } a;
                a.u[0] = cvt_pk_bf16(xv[m][2 * ks].x,     xv[m][2 * ks].y);
                a.u[1] = cvt_pk_bf16(xv[m][2 * ks].z,     xv[m][2 * ks].w);
                a.u[2] = cvt_pk_bf16(xv[m][2 * ks + 1].x, xv[m][2 * ks + 1].y);
                a.u[3] = cvt_pk_bf16(xv[m][2 * ks + 1].z, xv[m][2 * ks + 1].w);
                afs[m][ks] = a.v;
            }
        __builtin_amdgcn_s_setprio(1);
        #pragma unroll
        for (int nb = 0; nb < 6; nb++) {
            const int rb384 = browbase + nb * 16 * 384;
            #pragma unroll
            for (int ks = 0; ks < 2; ks++) {
                const bf16x8 bfr = *(const bf16x8*)&smem[rb384 +
                        (((8 * j + 4 * ks + g) ^ (i & 7)) << 3)];
                accP[0][nb] = __builtin_amdgcn_mfma_f32_16x16x32_bf16(afs[0][ks], bfr, accP[0][nb], 0, 0, 0);
                accP[1][nb] = __builtin_amdgcn_mfma_f32_16x16x32_bf16(afs[1][ks], bfr, accP[1][nb], 0, 0, 0);
            }
        }
        __builtin_amdgcn_s_setprio(0);
    }
    // all waves must finish reading Wl before it is overwritten by K/Q/V
    asm volatile("s_waitcnt lgkmcnt(0)\n\ts_barrier" ::: "memory");

    short* const Pb = smem;
    short* const Ks = smem + 10240;
    short* const Qs = smem + 26624;
    short* const Vt = smem + 43008;

    // ---- Epilogue: scatter K,Q (b16) and V (packed b64) to swizzled LDS ----
    #pragma unroll
    for (int m = 0; m < 2; m++) {
        const int row0 = 32 * wr + 16 * m + 4 * g;
        #pragma unroll
        for (int nb = 0; nb < 6; nb++) {
            const int gc = 96 * wc + 16 * nb;   // wave-uniform
            if (gc < 64) {
                #pragma unroll
                for (int r = 0; r < 4; r++)
                    Ks[swz64(row0 + r, gc + i)] = (short)f2bf(accP[m][nb][r]);
            } else if (gc < 128) {
                #pragma unroll
                for (int r = 0; r < 4; r++)
                    Qs[swz64(row0 + r, gc - 64 + i)] = (short)f2bf(accP[m][nb][r]);
            } else {
                const int hrow = gc - 128 + i;
                const int t0   = row0;
                bf16x4 pk;
                #pragma unroll
                for (int r = 0; r < 4; r++) pk[r] = (short)f2bf(accP[m][nb][r]);
                const int blk = t0 >> 3;
                *(bf16x4*)&Vt[hrow * 256 + (((blk & ~7) | ((blk ^ (hrow & 7)) & 7)) << 3) + (t0 & 7)] = pk;
            }
        }
    }
    asm volatile("s_waitcnt lgkmcnt(0)\n\ts_barrier" ::: "memory");

    // ---- Phase 2: causal attention (wave w owns rows [16w,16w+16)) ----
    const int rb = 16 * w;
    bf16x8 qf[2];
    #pragma unroll
    for (int ks = 0; ks < 2; ks++)
        qf[ks] = *(const bf16x8*)&Qs[(rb + i) * 64 + (((ks * 4 + g) ^ (i & 7)) << 3)];

    short* myP = Pb + w * 640;                 // [16][40] shorts, block-swizzled
    const float NEG_INF = -__builtin_inff();
    const int lim = w;

    f32x4 accS[16];
    #pragma unroll
    for (int nt = 0; nt < 16; nt++) accS[nt] = f32x4{0.f, 0.f, 0.f, 0.f};

    #pragma unroll
    for (int nt = 0; nt < 16; nt++) {
        if (nt <= lim) {
            #pragma unroll
            for (int ks = 0; ks < 2; ks++) {
                const bf16x8 kf = *(const bf16x8*)&Ks[(nt * 16 + i) * 64 + (((ks * 4 + g) ^ (i & 7)) << 3)];
                accS[nt] = __builtin_amdgcn_mfma_f32_16x16x32_bf16(qf[ks], kf, accS[nt], 0, 0, 0);
            }
        }
    }

    float mrow[4] = { NEG_INF, NEG_INF, NEG_INF, NEG_INF };
    #pragma unroll
    for (int nt = 0; nt < 16; nt++)
        #pragma unroll
        for (int r = 0; r < 4; r++) {
            const int col = nt * 16 + i;
            const int row = rb + 4 * g + r;
            float v = accS[nt][r] * SCALE_;
            v = (col <= row) ? v : NEG_INF;
            accS[nt][r] = v;
            mrow[r] = fmaxf(mrow[r], v);
        }
    #pragma unroll
    for (int r = 0; r < 4; r++)
        #pragma unroll
        for (int msk = 1; msk < 16; msk <<= 1)
            mrow[r] = fmaxf(mrow[r], __shfl_xor(mrow[r], msk, 64));

    float lsum[4] = { 0.f, 0.f, 0.f, 0.f };
    #pragma unroll
    for (int nt = 0; nt < 16; nt++)
        #pragma unroll
        for (int r = 0; r < 4; r++) {
            const float p = __expf(accS[nt][r] - mrow[r]);
            accS[nt][r] = p;
            lsum[r] += p;
        }
    #pragma unroll
    for (int r = 0; r < 4; r++)
        #pragma unroll
        for (int msk = 1; msk < 16; msk <<= 1)
            lsum[r] += __shfl_xor(lsum[r], msk, 64);

    f32x4 accO[4];
    #pragma unroll
    for (int ht = 0; ht < 4; ht++) accO[ht] = f32x4{0.f, 0.f, 0.f, 0.f};

    #pragma unroll
    for (int ck = 0; ck < 8; ck++) {
        if (2 * ck <= lim) {
            #pragma unroll
            for (int t2 = 0; t2 < 2; t2++)
                #pragma unroll
                for (int r = 0; r < 4; r++) {
                    const int q = 4 * g + r, kk = t2 * 16 + i;
                    myP[q * 40 + ((((kk >> 3) ^ (q >> 2)) & 3) << 3) + (kk & 7)] =
                        (short)f2bf(accS[2 * ck + t2][r]);
                }
            asm volatile("s_waitcnt lgkmcnt(0)" ::: "memory");
            const bf16x8 pf = *(const bf16x8*)&myP[i * 40 + (((g ^ (i >> 2)) & 3) << 3)];
            #pragma unroll
            for (int ht = 0; ht < 4; ht++) {
                const int hrow = ht * 16 + i;
                const int blk  = ck * 4 + g;
                const bf16x8 vf = *(const bf16x8*)&Vt[hrow * 256 +
                        (((blk & ~7) | ((blk ^ (hrow & 7)) & 7)) << 3)];
                accO[ht] = __builtin_amdgcn_mfma_f32_16x16x32_bf16(pf, vf, accO[ht], 0, 0, 0);
            }
        }
    }

    float inv[4];
    #pragma unroll
    for (int r = 0; r < 4; r++) inv[r] = 1.f / lsum[r];
    #pragma unroll
    for (int ht = 0; ht < 4; ht++)
        #pragma unroll
        for (int r = 0; r < 4; r++) {
            const int row = rb + 4 * g + r;
            out[((size_t)b * T_ + row) * H_ + ht * 16 + i] = accO[ht][r] * inv[r];
        }
}

extern "C" void kernel_launch(void* const* d_in, const int* in_sizes, int n_in,
                              void* d_out, int out_size, void* d_ws, size_t ws_size,
                              hipStream_t stream) {
    const float* x  = (const float*)d_in[0];
    const float* Wk = (const float*)d_in[1];
    const float* Wq = (const float*)d_in[2];
    const float* Wv = (const float*)d_in[3];
    float* out = (float*)d_out;
    (void)d_ws; (void)ws_size; (void)in_sizes; (void)n_in; (void)out_size;
    att_head_kernel<<<dim3(B_), dim3(1024), 0, stream>>>(x, Wk, Wq, Wv, out);
}

// Round 9
// 57.494 us; speedup vs baseline: 1.4072x; 1.4072x over previous
//
#include <hip/hip_runtime.h>
#include <hip/hip_bf16.h>

#define B_  512
#define T_  256
#define C_  384
#define H_  64
#define SCALE_ 0.05103103630798287f   // 384^-0.5

typedef float f32x4  __attribute__((ext_vector_type(4)));
typedef short bf16x8 __attribute__((ext_vector_type(8)));
typedef short bf16x4 __attribute__((ext_vector_type(4)));

__device__ __forceinline__ unsigned short f2bf(float f) {
    union { float f; unsigned u; } v; v.f = f;
    unsigned r = v.u + 0x7FFFu + ((v.u >> 16) & 1u);   // RNE
    return (unsigned short)(r >> 16);
}

__device__ __forceinline__ unsigned cvt_pk_bf16(float lo, float hi) {
    unsigned r;
    asm("v_cvt_pk_bf16_f32 %0, %1, %2" : "=v"(r) : "v"(lo), "v"(hi));
    return r;
}

// XOR-swizzled [R][64]-short tile index (row = 128 B = 8 x 16B blocks).
__device__ __forceinline__ int swz64(int row, int col) {
    return row * 64 + (((col >> 3) ^ (row & 7)) << 3) + (col & 7);
}

// LDS (shorts): smem[53760] = 107520 B.
//  Phase-1: wst0 [0,12288), wst1 [12288,24576)  (W^T k-chunk double buffer)
//  Phase-2 (alias, written after last wst read + barrier):
//    Ks[256][64] swz64      [0,     16384)
//    Vt[64][264]            [16384, 33280)   (V^T: rows h, cols t, +8 pad)
//    Pb 16 waves x 2x[16][40] [33280, 53760) (P^T double-buffered scratch)
//
// Phase 1: R3-verbatim (proven 60.2us). Phase 2: S^T orientation
// (mfma(K,Q) -> lane holds kv=4g+r, q=i), online softmax w/ defer-max,
// PV = mfma(V^T, P^T) software-pipelined through double-buffered myP.
// Q never block-shared: transposed through the wave's own Ks slice.
__global__ __launch_bounds__(1024, 4) void att_head_kernel(
    const float* __restrict__ x,  const float* __restrict__ Wk,
    const float* __restrict__ Wq, const float* __restrict__ Wv,
    float* __restrict__ out)
{
    __shared__ __align__(16) short smem[53760];
    short* const wst0 = smem;
    short* const wst1 = smem + 12288;
    short* const Ks   = smem;            // alias (live after phase 1)
    short* const Vt   = smem + 16384;
    short* const Pb   = smem + 33280;

    const int tid  = threadIdx.x;
    const int b    = blockIdx.x;
    const int w    = tid >> 6;        // 0..15
    const int lane = tid & 63;
    const int g    = lane >> 4;
    const int i    = lane & 15;
    const int rb   = 16 * w;          // this wave's Q-row strip base

    const float* xb = x + (size_t)b * T_ * C_;
    const float* Wm[3] = { Wk, Wq, Wv };

    f32x4 accP[12];
    #pragma unroll
    for (int nb = 0; nb < 12; nb++) accP[nb] = f32x4{0.f, 0.f, 0.f, 0.f};

    // per-lane global base for this wave's A-rows
    const float* xrow = xb + (size_t)(rb + i) * C_ + g * 8;

    // ---- W staging (R3): thread (w, lane): rows m*64+lane, k-quad w, swizzled b64 ----
    auto stageW = [&](int kc, short* buf) {
        #pragma unroll
        for (int m = 0; m < 3; m++) {
            const float* Wp = Wm[m] + (size_t)(kc + w * 4) * H_ + lane;
            bf16x4 pk;
            #pragma unroll
            for (int jj = 0; jj < 4; jj++) pk[jj] = (short)f2bf(Wp[jj * H_]);
            const int row = m * 64 + lane;
            const int k0  = w * 4;
            *(bf16x4*)&buf[row * 64 + (((k0 >> 3) ^ (row & 7)) << 3) + (k0 & 7)] = pk;
        }
    };

    // ---------------- Phase 1 (R3 verbatim): 6 chunks of k=64 ----------------
    float4 xr[2][4];
    #pragma unroll
    for (int ks = 0; ks < 2; ks++)
        #pragma unroll
        for (int h = 0; h < 2; h++)
            xr[0][ks * 2 + h] = *(const float4*)(xrow + ks * 32 + h * 4);
    stageW(0, wst0);
    asm volatile("s_waitcnt lgkmcnt(0)\n\ts_barrier" ::: "memory");

    #pragma unroll
    for (int j = 0; j < 6; j++) {
        const int par = j & 1;
        short* cur = par ? wst1 : wst0;
        if (j < 5) {
            #pragma unroll
            for (int ks = 0; ks < 2; ks++)
                #pragma unroll
                for (int h = 0; h < 2; h++)
                    xr[par ^ 1][ks * 2 + h] = *(const float4*)(xrow + (j + 1) * 64 + ks * 32 + h * 4);
            stageW((j + 1) * 64, par ? wst0 : wst1);
        }
        bf16x8 afs[2];
        #pragma unroll
        for (int ks = 0; ks < 2; ks++)
            #pragma unroll
            for (int h = 0; h < 2; h++) {
                const float4 v = xr[par][ks * 2 + h];
                afs[ks][h * 4 + 0] = (short)f2bf(v.x);
                afs[ks][h * 4 + 1] = (short)f2bf(v.y);
                afs[ks][h * 4 + 2] = (short)f2bf(v.z);
                afs[ks][h * 4 + 3] = (short)f2bf(v.w);
            }
        #pragma unroll
        for (int nb = 0; nb < 12; nb++) {
            #pragma unroll
            for (int ks = 0; ks < 2; ks++) {
                const int brow = nb * 16 + i;
                const bf16x8 bfr = *(const bf16x8*)&cur[brow * 64 + (((ks * 4 + g) ^ (i & 7)) << 3)];
                accP[nb] = __builtin_amdgcn_mfma_f32_16x16x32_bf16(afs[ks], bfr, accP[nb], 0, 0, 0);
            }
        }
        asm volatile("s_waitcnt lgkmcnt(0)\n\ts_barrier" ::: "memory");
    }
    // wst dead from here (barrier above drained all reads)

    // ---------------- Epilogue ----------------
    // (1) Q -> own Ks slice (rows rb..rb+16), wave-local transpose
    #pragma unroll
    for (int nb = 0; nb < 4; nb++)
        #pragma unroll
        for (int r = 0; r < 4; r++)
            Ks[swz64(rb + 4 * g + r, 16 * nb + i)] = (short)f2bf(accP[4 + nb][r]);
    asm volatile("s_waitcnt lgkmcnt(0)" ::: "memory");
    bf16x8 qf[2];
    #pragma unroll
    for (int ks = 0; ks < 2; ks++)
        qf[ks] = *(const bf16x8*)&Ks[(rb + i) * 64 + (((4 * ks + g) ^ (i & 7)) << 3)];
    asm volatile("s_waitcnt lgkmcnt(0)" ::: "memory");   // qf landed before overwrite
    // (2) K -> same slice (b16 scatter)
    #pragma unroll
    for (int nb = 0; nb < 4; nb++)
        #pragma unroll
        for (int r = 0; r < 4; r++)
            Ks[swz64(rb + 4 * g + r, 16 * nb + i)] = (short)f2bf(accP[nb][r]);
    // (3) V -> Vt[h][t], packed b64 (r-consecutive t)
    #pragma unroll
    for (int nb = 0; nb < 4; nb++) {
        bf16x4 pk;
        #pragma unroll
        for (int r = 0; r < 4; r++) pk[r] = (short)f2bf(accP[8 + nb][r]);
        *(bf16x4*)&Vt[(16 * nb + i) * 264 + rb + 4 * g] = pk;
    }
    asm volatile("s_waitcnt lgkmcnt(0)\n\ts_barrier" ::: "memory");

    // ---------------- Phase 2: online causal attention, S^T orientation ----------
    short* const myP = Pb + w * 1280;    // two [16][40] buffers
    const float NEG_INF = -__builtin_inff();
    float mrun = NEG_INF, lrun = 0.f;
    f32x4 accO[4];
    #pragma unroll
    for (int ht = 0; ht < 4; ht++) accO[ht] = f32x4{0.f, 0.f, 0.f, 0.f};

    auto PVADD = [&](int bufsel, int ck) {
        const bf16x8 pf = *(const bf16x8*)&myP[bufsel * 640 + i * 40 + 8 * g];
        #pragma unroll
        for (int ht = 0; ht < 4; ht++) {
            const bf16x8 vf = *(const bf16x8*)&Vt[(16 * ht + i) * 264 + 32 * ck + 8 * g];
            accO[ht] = __builtin_amdgcn_mfma_f32_16x16x32_bf16(vf, pf, accO[ht], 0, 0, 0);
        }
    };

    const int npair = w >> 1;            // last pair index; pair p = tiles 2p, 2p+1
    #pragma unroll
    for (int p = 0; p < 8; p++) {
        if (p <= npair) {                // wave-uniform
            // QK^T (S^T tiles): lane holds (kv = 16*(2p+s)+4g+r, q = rb+i)
            f32x4 sA[2];
            sA[0] = f32x4{0.f, 0.f, 0.f, 0.f};
            sA[1] = f32x4{0.f, 0.f, 0.f, 0.f};
            #pragma unroll
            for (int s = 0; s < 2; s++) {
                const int nt = 2 * p + s;
                if (nt <= w) {           // wave-uniform
                    #pragma unroll
                    for (int ks = 0; ks < 2; ks++) {
                        const bf16x8 kfr = *(const bf16x8*)&Ks[(16 * nt + i) * 64 +
                                (((4 * ks + g) ^ (i & 7)) << 3)];
                        sA[s] = __builtin_amdgcn_mfma_f32_16x16x32_bf16(kfr, qf[ks], sA[s], 0, 0, 0);
                    }
                }
            }
            // PV of previous pair (pipelined: its myP writes drained under this QK)
            if (p > 0) PVADD((p - 1) & 1, p - 1);

            // scale + causal mask + tile max
            float mt = NEG_INF;
            #pragma unroll
            for (int s = 0; s < 2; s++)
                #pragma unroll
                for (int r = 0; r < 4; r++) {
                    const int kv = 16 * (2 * p + s) + 4 * g + r;
                    const bool ok = (2 * p + s <= w) && (kv <= rb + i);
                    const float v = ok ? sA[s][r] * SCALE_ : NEG_INF;
                    sA[s][r] = v;
                    mt = fmaxf(mt, v);
                }
            mt = fmaxf(mt, __shfl_xor(mt, 16, 64));
            mt = fmaxf(mt, __shfl_xor(mt, 32, 64));   // uniform across g for each q

            // defer-max (THR=8): rescale only when max grew past threshold
            if (!__all(mt <= mrun + 8.0f)) {
                const float mnew = fmaxf(mrun, mt);
                const float f = __expf(mrun - mnew);
                mrun = mnew; lrun *= f;
                #pragma unroll
                for (int ht = 0; ht < 4; ht++)
                    #pragma unroll
                    for (int r = 0; r < 4; r++) accO[ht][r] *= f;
            }
            // exp + accumulate l + pack P^T pair into myP[p&1]
            #pragma unroll
            for (int s = 0; s < 2; s++) {
                const float p0 = __expf(sA[s][0] - mrun);
                const float p1 = __expf(sA[s][1] - mrun);
                const float p2 = __expf(sA[s][2] - mrun);
                const float p3 = __expf(sA[s][3] - mrun);
                lrun += (p0 + p1) + (p2 + p3);
                union { bf16x4 v; unsigned u[2]; } pk;
                pk.u[0] = cvt_pk_bf16(p0, p1);
                pk.u[1] = cvt_pk_bf16(p2, p3);
                *(bf16x4*)&myP[(p & 1) * 640 + i * 40 + 16 * s + 4 * g] = pk.v;
            }
        }
    }
    PVADD(npair & 1, npair);             // drain last pair

    // final denominator (sum across the 4 g-lanes of column q)
    lrun += __shfl_xor(lrun, 16, 64);
    lrun += __shfl_xor(lrun, 32, 64);
    const float inv = 1.f / lrun;

    // store O^T: lane holds (h = 16ht+4g+r, q = rb+i) -> float4 per ht
    float* orow = out + ((size_t)b * T_ + rb + i) * H_;
    #pragma unroll
    for (int ht = 0; ht < 4; ht++) {
        float4 o;
        o.x = accO[ht][0] * inv;
        o.y = accO[ht][1] * inv;
        o.z = accO[ht][2] * inv;
        o.w = accO[ht][3] * inv;
        *(float4*)&orow[16 * ht + 4 * g] = o;
    }
}

extern "C" void kernel_launch(void* const* d_in, const int* in_sizes, int n_in,
                              void* d_out, int out_size, void* d_ws, size_t ws_size,
                              hipStream_t stream) {
    const float* x  = (const float*)d_in[0];
    const float* Wk = (const float*)d_in[1];
    const float* Wq = (const float*)d_in[2];
    const float* Wv = (const float*)d_in[3];
    float* out = (float*)d_out;
    (void)d_ws; (void)ws_size; (void)in_sizes; (void)n_in; (void)out_size;
    att_head_kernel<<<dim3(B_), dim3(1024), 0, stream>>>(x, Wk, Wq, Wv, out);
}